// Round 4
// baseline (407.817 us; speedup 1.0000x reference)
//
#include <hip/hip_runtime.h>
#include <math.h>

#define NB 16
#define LL 512
#define CIN 32
#define DM 128
#define DS 16
#define DI 256
#define DTR 8
#define NCOL 3072
#define KTOT 65536
#define ROWS 8192
#define CH 32            // scan chunks
#define CLEN 16          // steps per chunk
#define KC 128           // k_final k-chunk
#define KS 512           // k_final splits
#define OUTSZ 49152

__device__ __forceinline__ float sigmoidf_(float x){ return 1.f/(1.f+expf(-x)); }
__device__ __forceinline__ float softplusf_(float x){ return (x > 20.f) ? x : log1pf(expf(x)); }

// h = x @ W_in + b_in   (ROWS x 128, K=32)
__global__ void k_in(const float* __restrict__ x, const float* __restrict__ W,
                     const float* __restrict__ bias, float* __restrict__ h) {
  int idx = blockIdx.x*256 + threadIdx.x;
  int r = idx >> 7, c = idx & 127;
  const float* xr = x + r*CIN;
  float acc = bias[c];
  #pragma unroll
  for (int k=0;k<CIN;k++) acc = fmaf(xr[k], W[k*DM+c], acc);
  h[idx] = acc;
}

// xz = h @ W_inproj -> u_pre (cols 0..255), z (cols 256..511). K=128.
__global__ void k_inproj(const float* __restrict__ h, const float* __restrict__ W,
                         float* __restrict__ u_pre, float* __restrict__ z) {
  int t = threadIdx.x;
  int c0 = (t & 127)*4;
  int r0 = blockIdx.x*8 + (t>>7)*4;
  float acc[4][4] = {};
  for (int k=0;k<DM;k++) {
    float4 w = *(const float4*)(W + k*512 + c0);
    #pragma unroll
    for (int i=0;i<4;i++) {
      float hv = h[(r0+i)*DM + k];
      acc[i][0]=fmaf(hv,w.x,acc[i][0]); acc[i][1]=fmaf(hv,w.y,acc[i][1]);
      acc[i][2]=fmaf(hv,w.z,acc[i][2]); acc[i][3]=fmaf(hv,w.w,acc[i][3]);
    }
  }
  #pragma unroll
  for (int i=0;i<4;i++) {
    float4 v = make_float4(acc[i][0],acc[i][1],acc[i][2],acc[i][3]);
    if (c0 < 256) *(float4*)(u_pre + (r0+i)*DI + c0) = v;
    else          *(float4*)(z     + (r0+i)*DI + (c0-256)) = v;
  }
}

// causal depthwise conv (k=4) + bias + silu
__global__ void k_conv(const float* __restrict__ u_pre, const float* __restrict__ cw,
                       const float* __restrict__ cb, float* __restrict__ u) {
  int idx = blockIdx.x*256 + threadIdx.x; // NB*LL*DI
  int d = idx & 255;
  int l = (idx >> 8) & 511;
  int b = idx >> 17;
  float s = cb[d];
  #pragma unroll
  for (int j=0;j<4;j++) {
    int li = l - 3 + j;
    if (li >= 0) s = fmaf(cw[d*4+j], u_pre[(((b<<9)+li)<<8) + d], s);
  }
  u[idx] = s * sigmoidf_(s);
}

// xdbc = u @ W_xproj  (ROWS x 40, K=256)
__global__ void k_xproj(const float* __restrict__ u, const float* __restrict__ W,
                        float* __restrict__ xdbc) {
  int idx = blockIdx.x*256 + threadIdx.x; // ROWS*40
  int r = idx / 40, c = idx - r*40;
  const float4* ur4 = (const float4*)(u + r*DI);
  float acc = 0.f;
  #pragma unroll 8
  for (int k4=0;k4<DI/4;k4++) {
    float4 uv = ur4[k4];
    acc = fmaf(uv.x, W[(k4*4+0)*40+c], acc);
    acc = fmaf(uv.y, W[(k4*4+1)*40+c], acc);
    acc = fmaf(uv.z, W[(k4*4+2)*40+c], acc);
    acc = fmaf(uv.w, W[(k4*4+3)*40+c], acc);
  }
  xdbc[idx] = acc;
}

// scan pass 1: per (b,chunk) block, thread=d. dt recomputed inline.
__global__ void k_scan1(const float* __restrict__ u, const float* __restrict__ xdbc,
                        const float* __restrict__ Wdt, const float* __restrict__ bdt,
                        const float* __restrict__ A_log,
                        float* __restrict__ Hc, float* __restrict__ Sdt) {
  int b = blockIdx.x >> 5, c = blockIdx.x & 31, d = threadIdx.x;
  float A[16]; float hs[16];
  #pragma unroll
  for (int n=0;n<16;n++) { A[n] = -expf(A_log[d*16+n]); hs[n]=0.f; }
  float wdt[DTR];
  #pragma unroll
  for (int j=0;j<DTR;j++) wdt[j] = Wdt[j*DI+d];
  float bdtv = bdt[d];
  float sdt = 0.f;
  int l0 = c*CLEN;
  for (int l=l0; l<l0+CLEN; ++l) {
    int row = (b<<9) + l;
    const float* xr = xdbc + row*40;
    float acc = bdtv;
    #pragma unroll
    for (int j=0;j<DTR;j++) acc = fmaf(xr[j], wdt[j], acc);
    float dtv = softplusf_(acc);
    float uv  = u[(row<<8) + d];
    sdt += dtv;
    float du = dtv*uv;
    const float* Bp = xr + DTR;
    #pragma unroll
    for (int n=0;n<16;n++) {
      float a = expf(dtv*A[n]);
      hs[n] = fmaf(a, hs[n], du*Bp[n]);
    }
  }
  int bd = (b<<8) + d;
  int base = (bd*CH + c)*16;
  #pragma unroll
  for (int n=0;n<16;n++) Hc[base+n] = hs[n];
  Sdt[bd*CH + c] = sdt;
}

// pass 2: one thread per (b,d,n) chain; combine CH chunks; store chunk start states
__global__ void k_scan2(const float* __restrict__ A_log, const float* __restrict__ Hc,
                        const float* __restrict__ Sdt, float* __restrict__ Hst) {
  int idx = blockIdx.x*256 + threadIdx.x;   // NB*DI*DS = 65536
  int n  = idx & 15;
  int bd = idx >> 4;
  int d  = bd & 255;
  float A = -expf(A_log[d*16+n]);
  float hs = 0.f;
  int base = bd*CH*16;
  #pragma unroll
  for (int c=0;c<CH;c++) {
    Hst[base + c*16 + n] = hs;
    float sdt = Sdt[bd*CH + c];
    hs = fmaf(expf(A*sdt), hs, Hc[base + c*16 + n]);
  }
}

// pass 3: replay each chunk from correct start state; fuse y = (scan + u*D)*silu(z)
__global__ void k_scan3(const float* __restrict__ u, const float* __restrict__ z,
                        const float* __restrict__ xdbc,
                        const float* __restrict__ Wdt, const float* __restrict__ bdt,
                        const float* __restrict__ A_log, const float* __restrict__ Dp,
                        const float* __restrict__ Hst, float* __restrict__ ym) {
  int b = blockIdx.x >> 5, c = blockIdx.x & 31, d = threadIdx.x;
  int bd = (b<<8) + d;
  int base = (bd*CH + c)*16;
  float A[16]; float hs[16];
  #pragma unroll
  for (int n=0;n<16;n++) { A[n] = -expf(A_log[d*16+n]); hs[n] = Hst[base+n]; }
  float wdt[DTR];
  #pragma unroll
  for (int j=0;j<DTR;j++) wdt[j] = Wdt[j*DI+d];
  float bdtv = bdt[d];
  float Dv = Dp[d];
  int l0 = c*CLEN;
  for (int l=l0; l<l0+CLEN; ++l) {
    int row = (b<<9) + l;
    const float* xr = xdbc + row*40;
    float acc = bdtv;
    #pragma unroll
    for (int j=0;j<DTR;j++) acc = fmaf(xr[j], wdt[j], acc);
    float dtv = softplusf_(acc);
    float uv  = u[(row<<8) + d];
    float zv  = z[(row<<8) + d];
    float du = dtv*uv;
    const float* Bp = xr + DTR;
    const float* Cp = xr + DTR + DS;
    float y = 0.f;
    #pragma unroll
    for (int n=0;n<16;n++) {
      float a = expf(dtv*A[n]);
      hs[n] = fmaf(a, hs[n], du*Bp[n]);
      y = fmaf(hs[n], Cp[n], y);
    }
    y = fmaf(uv, Dv, y);
    ym[(row<<8)+d] = y * (zv * sigmoidf_(zv));
  }
}

// m_out = ym @ W_out (ROWS x 128, K=256). 1024 blocks, 4 rows x 1 col per thread.
__global__ void k_out(const float* __restrict__ ym, const float* __restrict__ W,
                      float* __restrict__ mo) {
  int t = threadIdx.x;
  int c  = t & 127;
  int r0 = blockIdx.x*8 + (t>>7)*4;
  float acc[4] = {0.f,0.f,0.f,0.f};
  #pragma unroll 4
  for (int k=0;k<DI;k++) {
    float w = W[k*DM + c];
    #pragma unroll
    for (int i=0;i<4;i++) acc[i] = fmaf(ym[(r0+i)*DI + k], w, acc[i]);
  }
  #pragma unroll
  for (int i=0;i<4;i++) mo[(r0+i)*DM + c] = acc[i];
}

// final: pred partials = flat(16 x 65536) @ W_outproj(65536 x 3072), split-K.
// Each thread: 4 cols x all 16 rows. Wave reads 1KB contiguous W per k.
__global__ void __launch_bounds__(256) k_final(
    const float* __restrict__ flat, const float* __restrict__ W,
    float* __restrict__ part) {
  __shared__ float lds[KC][16];            // transposed: [kk][b], 8 KB
  int t = threadIdx.x;
  int n0 = blockIdx.x * 1024;              // 3 n-tiles of 1024 cols
  int k0 = blockIdx.y * KC;                // KS k-splits of KC
  // stage flat chunk (16 rows x KC k) transposed into LDS; bb fast -> 4-way conflict max
  for (int i = t; i < 16*(KC/4); i += 256) {
    int bb  = i & 15;
    int kk4 = i >> 4;
    float4 v = *(const float4*)(flat + bb*KTOT + k0 + kk4*4);
    lds[kk4*4+0][bb] = v.x; lds[kk4*4+1][bb] = v.y;
    lds[kk4*4+2][bb] = v.z; lds[kk4*4+3][bb] = v.w;
  }
  __syncthreads();
  int c0 = n0 + t*4;
  float4 acc[16];
  #pragma unroll
  for (int b=0;b<16;b++) acc[b] = make_float4(0.f,0.f,0.f,0.f);
  const float* Wp = W + (size_t)k0*NCOL + c0;
  for (int kk=0; kk<KC; kk+=2) {
    float4 w0 = *(const float4*)(Wp + (size_t)kk*NCOL);
    float4 w1 = *(const float4*)(Wp + (size_t)(kk+1)*NCOL);
    const float4* f0 = (const float4*)&lds[kk][0];
    const float4* f1 = (const float4*)&lds[kk+1][0];
    #pragma unroll
    for (int q=0;q<4;q++) {
      float4 fa = f0[q], fb = f1[q];
      float fs[8] = {fa.x,fa.y,fa.z,fa.w, fb.x,fb.y,fb.z,fb.w};
      #pragma unroll
      for (int j=0;j<4;j++) {
        int b = q*4+j;
        acc[b].x=fmaf(fs[j],w0.x,acc[b].x); acc[b].y=fmaf(fs[j],w0.y,acc[b].y);
        acc[b].z=fmaf(fs[j],w0.z,acc[b].z); acc[b].w=fmaf(fs[j],w0.w,acc[b].w);
        acc[b].x=fmaf(fs[4+j],w1.x,acc[b].x); acc[b].y=fmaf(fs[4+j],w1.y,acc[b].y);
        acc[b].z=fmaf(fs[4+j],w1.z,acc[b].z); acc[b].w=fmaf(fs[4+j],w1.w,acc[b].w);
      }
    }
  }
  float* p = part + (size_t)blockIdx.y*OUTSZ;
  #pragma unroll
  for (int b=0;b<16;b++) *(float4*)(p + b*NCOL + c0) = acc[b];
}

// reduce stage 1: sum 128 splits each -> part2[4][OUTSZ]
__global__ void k_reduce1(const float* __restrict__ part, float* __restrict__ part2) {
  int idx = blockIdx.x*256 + threadIdx.x;  // OUTSZ
  int y = blockIdx.y;                      // 0..3
  const float* p = part + (size_t)y*128*OUTSZ + idx;
  float acc = 0.f;
  #pragma unroll 8
  for (int s=0;s<128;s++) acc += p[(size_t)s*OUTSZ];
  part2[(size_t)y*OUTSZ + idx] = acc;
}

// reduce stage 2: sum 4 + bias
__global__ void k_reduce2(const float* __restrict__ part2, const float* __restrict__ bias,
                          float* __restrict__ out) {
  int idx = blockIdx.x*256 + threadIdx.x;  // OUTSZ
  float acc = bias[idx % NCOL];
  #pragma unroll
  for (int y=0;y<4;y++) acc += part2[(size_t)y*OUTSZ + idx];
  out[idx] = acc;
}

extern "C" void kernel_launch(void* const* d_in, const int* in_sizes, int n_in,
                              void* d_out, int out_size, void* d_ws, size_t ws_size,
                              hipStream_t stream) {
  const float* x        = (const float*)d_in[0];
  const float* W_in     = (const float*)d_in[1];
  const float* b_in     = (const float*)d_in[2];
  const float* W_inproj = (const float*)d_in[3];
  const float* conv_w   = (const float*)d_in[4];
  const float* conv_b   = (const float*)d_in[5];
  const float* W_xproj  = (const float*)d_in[6];
  const float* W_dt     = (const float*)d_in[7];
  const float* b_dt     = (const float*)d_in[8];
  const float* A_log    = (const float*)d_in[9];
  const float* Dp       = (const float*)d_in[10];
  const float* W_out    = (const float*)d_in[11];
  const float* W_outproj= (const float*)d_in[12];
  const float* b_outproj= (const float*)d_in[13];
  float* out = (float*)d_out;
  float* ws  = (float*)d_ws;

  float* h     = ws;            // 1048576
  float* u_pre = ws + 1048576;  // 2097152
  float* z     = ws + 3145728;  // 2097152
  float* u     = ws + 5242880;  // 2097152
  float* xdbc  = ws + 7340032;  // 327680
  float* Hc    = ws + 7667712;  // 2097152 (NB*DI*CH*16)
  float* Sdt   = ws + 9764864;  // 131072
  float* Hst   = ws + 9895936;  // 2097152
  float* ym    = ws + 11993088; // 2097152
  float* mo    = ws + 14090240; // 1048576
  float* part  = ws + 15138816; // 25165824 (KS*OUTSZ)
  float* part2 = ws + 40304640; // 196608   -> total ~162 MB

  k_in     <<<4096, 256, 0, stream>>>(x, W_in, b_in, h);
  k_inproj <<<1024, 256, 0, stream>>>(h, W_inproj, u_pre, z);
  k_conv   <<<8192, 256, 0, stream>>>(u_pre, conv_w, conv_b, u);
  k_xproj  <<<1280, 256, 0, stream>>>(u, W_xproj, xdbc);
  k_scan1  <<<512,  256, 0, stream>>>(u, xdbc, W_dt, b_dt, A_log, Hc, Sdt);
  k_scan2  <<<256,  256, 0, stream>>>(A_log, Hc, Sdt, Hst);
  k_scan3  <<<512,  256, 0, stream>>>(u, z, xdbc, W_dt, b_dt, A_log, Dp, Hst, ym);
  k_out    <<<1024, 256, 0, stream>>>(ym, W_out, mo);
  k_final  <<<dim3(3, KS), 256, 0, stream>>>(mo, W_outproj, part);
  k_reduce1<<<dim3(192, 4), 256, 0, stream>>>(part, part2);
  k_reduce2<<<192,  256, 0, stream>>>(part2, b_outproj, out);
}

// Round 5
// 367.287 us; speedup vs baseline: 1.1103x; 1.1103x over previous
//
#include <hip/hip_runtime.h>
#include <math.h>

#define NB 16
#define LL 512
#define CIN 32
#define DM 128
#define DS 16
#define DI 256
#define DTR 8
#define NCOL 3072
#define KTOT 65536
#define ROWS 8192
#define CH 32            // scan chunks
#define CLEN 16          // steps per chunk
#define KC 256           // k_final k-chunk
#define KS 256           // k_final splits
#define OUTSZ 49152

__device__ __forceinline__ float sigmoidf_(float x){ return 1.f/(1.f+expf(-x)); }
__device__ __forceinline__ float softplusf_(float x){ return (x > 20.f) ? x : log1pf(expf(x)); }

// h = x @ W_in + b_in   (ROWS x 128, K=32)
__global__ void k_in(const float* __restrict__ x, const float* __restrict__ W,
                     const float* __restrict__ bias, float* __restrict__ h) {
  int idx = blockIdx.x*256 + threadIdx.x;
  int r = idx >> 7, c = idx & 127;
  const float* xr = x + r*CIN;
  float acc = bias[c];
  #pragma unroll
  for (int k=0;k<CIN;k++) acc = fmaf(xr[k], W[k*DM+c], acc);
  h[idx] = acc;
}

// xz = h @ W_inproj -> u_pre (cols 0..255), z (cols 256..511). K=128.
__global__ void k_inproj(const float* __restrict__ h, const float* __restrict__ W,
                         float* __restrict__ u_pre, float* __restrict__ z) {
  int t = threadIdx.x;
  int c0 = (t & 127)*4;
  int r0 = blockIdx.x*8 + (t>>7)*4;
  float acc[4][4] = {};
  for (int k=0;k<DM;k++) {
    float4 w = *(const float4*)(W + k*512 + c0);
    #pragma unroll
    for (int i=0;i<4;i++) {
      float hv = h[(r0+i)*DM + k];
      acc[i][0]=fmaf(hv,w.x,acc[i][0]); acc[i][1]=fmaf(hv,w.y,acc[i][1]);
      acc[i][2]=fmaf(hv,w.z,acc[i][2]); acc[i][3]=fmaf(hv,w.w,acc[i][3]);
    }
  }
  #pragma unroll
  for (int i=0;i<4;i++) {
    float4 v = make_float4(acc[i][0],acc[i][1],acc[i][2],acc[i][3]);
    if (c0 < 256) *(float4*)(u_pre + (r0+i)*DI + c0) = v;
    else          *(float4*)(z     + (r0+i)*DI + (c0-256)) = v;
  }
}

// causal depthwise conv (k=4) + bias + silu
__global__ void k_conv(const float* __restrict__ u_pre, const float* __restrict__ cw,
                       const float* __restrict__ cb, float* __restrict__ u) {
  int idx = blockIdx.x*256 + threadIdx.x; // NB*LL*DI
  int d = idx & 255;
  int l = (idx >> 8) & 511;
  int b = idx >> 17;
  float s = cb[d];
  #pragma unroll
  for (int j=0;j<4;j++) {
    int li = l - 3 + j;
    if (li >= 0) s = fmaf(cw[d*4+j], u_pre[(((b<<9)+li)<<8) + d], s);
  }
  u[idx] = s * sigmoidf_(s);
}

// xdbc = u @ W_xproj  (ROWS x 40, K=256)
__global__ void k_xproj(const float* __restrict__ u, const float* __restrict__ W,
                        float* __restrict__ xdbc) {
  int idx = blockIdx.x*256 + threadIdx.x; // ROWS*40
  int r = idx / 40, c = idx - r*40;
  const float4* ur4 = (const float4*)(u + r*DI);
  float acc = 0.f;
  #pragma unroll 8
  for (int k4=0;k4<DI/4;k4++) {
    float4 uv = ur4[k4];
    acc = fmaf(uv.x, W[(k4*4+0)*40+c], acc);
    acc = fmaf(uv.y, W[(k4*4+1)*40+c], acc);
    acc = fmaf(uv.z, W[(k4*4+2)*40+c], acc);
    acc = fmaf(uv.w, W[(k4*4+3)*40+c], acc);
  }
  xdbc[idx] = acc;
}

// scan pass 1: per (b,chunk) block, thread=d. dt recomputed inline.
__global__ void k_scan1(const float* __restrict__ u, const float* __restrict__ xdbc,
                        const float* __restrict__ Wdt, const float* __restrict__ bdt,
                        const float* __restrict__ A_log,
                        float* __restrict__ Hc, float* __restrict__ Sdt) {
  int b = blockIdx.x >> 5, c = blockIdx.x & 31, d = threadIdx.x;
  float A[16]; float hs[16];
  #pragma unroll
  for (int n=0;n<16;n++) { A[n] = -expf(A_log[d*16+n]); hs[n]=0.f; }
  float wdt[DTR];
  #pragma unroll
  for (int j=0;j<DTR;j++) wdt[j] = Wdt[j*DI+d];
  float bdtv = bdt[d];
  float sdt = 0.f;
  int l0 = c*CLEN;
  for (int l=l0; l<l0+CLEN; ++l) {
    int row = (b<<9) + l;
    const float* xr = xdbc + row*40;
    float acc = bdtv;
    #pragma unroll
    for (int j=0;j<DTR;j++) acc = fmaf(xr[j], wdt[j], acc);
    float dtv = softplusf_(acc);
    float uv  = u[(row<<8) + d];
    sdt += dtv;
    float du = dtv*uv;
    const float* Bp = xr + DTR;
    #pragma unroll
    for (int n=0;n<16;n++) {
      float a = expf(dtv*A[n]);
      hs[n] = fmaf(a, hs[n], du*Bp[n]);
    }
  }
  int bd = (b<<8) + d;
  int base = (bd*CH + c)*16;
  #pragma unroll
  for (int n=0;n<16;n++) Hc[base+n] = hs[n];
  Sdt[bd*CH + c] = sdt;
}

// pass 2: one thread per (b,d,n) chain; combine CH chunks; store chunk start states
__global__ void k_scan2(const float* __restrict__ A_log, const float* __restrict__ Hc,
                        const float* __restrict__ Sdt, float* __restrict__ Hst) {
  int idx = blockIdx.x*256 + threadIdx.x;   // NB*DI*DS = 65536
  int n  = idx & 15;
  int bd = idx >> 4;
  int d  = bd & 255;
  float A = -expf(A_log[d*16+n]);
  float hs = 0.f;
  int base = bd*CH*16;
  #pragma unroll
  for (int c=0;c<CH;c++) {
    Hst[base + c*16 + n] = hs;
    float sdt = Sdt[bd*CH + c];
    hs = fmaf(expf(A*sdt), hs, Hc[base + c*16 + n]);
  }
}

// pass 3: replay each chunk from correct start state; fuse y = (scan + u*D)*silu(z)
__global__ void k_scan3(const float* __restrict__ u, const float* __restrict__ z,
                        const float* __restrict__ xdbc,
                        const float* __restrict__ Wdt, const float* __restrict__ bdt,
                        const float* __restrict__ A_log, const float* __restrict__ Dp,
                        const float* __restrict__ Hst, float* __restrict__ ym) {
  int b = blockIdx.x >> 5, c = blockIdx.x & 31, d = threadIdx.x;
  int bd = (b<<8) + d;
  int base = (bd*CH + c)*16;
  float A[16]; float hs[16];
  #pragma unroll
  for (int n=0;n<16;n++) { A[n] = -expf(A_log[d*16+n]); hs[n] = Hst[base+n]; }
  float wdt[DTR];
  #pragma unroll
  for (int j=0;j<DTR;j++) wdt[j] = Wdt[j*DI+d];
  float bdtv = bdt[d];
  float Dv = Dp[d];
  int l0 = c*CLEN;
  for (int l=l0; l<l0+CLEN; ++l) {
    int row = (b<<9) + l;
    const float* xr = xdbc + row*40;
    float acc = bdtv;
    #pragma unroll
    for (int j=0;j<DTR;j++) acc = fmaf(xr[j], wdt[j], acc);
    float dtv = softplusf_(acc);
    float uv  = u[(row<<8) + d];
    float zv  = z[(row<<8) + d];
    float du = dtv*uv;
    const float* Bp = xr + DTR;
    const float* Cp = xr + DTR + DS;
    float y = 0.f;
    #pragma unroll
    for (int n=0;n<16;n++) {
      float a = expf(dtv*A[n]);
      hs[n] = fmaf(a, hs[n], du*Bp[n]);
      y = fmaf(hs[n], Cp[n], y);
    }
    y = fmaf(uv, Dv, y);
    ym[(row<<8)+d] = y * (zv * sigmoidf_(zv));
  }
}

// m_out = ym @ W_out (ROWS x 128, K=256). 1024 blocks, 4 rows x 1 col per thread.
__global__ void k_out(const float* __restrict__ ym, const float* __restrict__ W,
                      float* __restrict__ mo) {
  int t = threadIdx.x;
  int c  = t & 127;
  int r0 = blockIdx.x*8 + (t>>7)*4;
  float acc[4] = {0.f,0.f,0.f,0.f};
  #pragma unroll 4
  for (int k=0;k<DI;k++) {
    float w = W[k*DM + c];
    #pragma unroll
    for (int i=0;i<4;i++) acc[i] = fmaf(ym[(r0+i)*DI + k], w, acc[i]);
  }
  #pragma unroll
  for (int i=0;i<4;i++) mo[(r0+i)*DM + c] = acc[i];
}

// final: pred partials = flat(16 x 65536) @ W_outproj(65536 x 3072), split-K.
// Each thread: 2 cols x all 16 rows (32 acc VGPRs). 6 n-tiles x 256 splits =
// 1536 blocks (6/CU). Wave reads 512B contiguous W per k.
__global__ void __launch_bounds__(256) k_final(
    const float* __restrict__ flat, const float* __restrict__ W,
    float* __restrict__ part) {
  __shared__ float lds[KC][16];            // transposed: [kk][b], 16 KB
  int t = threadIdx.x;
  int n0 = blockIdx.x * 512;               // 6 n-tiles of 512 cols
  int k0 = blockIdx.y * KC;                // KS k-splits of KC
  // stage flat chunk (16 rows x KC k) transposed into LDS
  for (int i = t; i < 16*(KC/4); i += 256) {
    int bb  = i & 15;
    int kk4 = i >> 4;
    float4 v = *(const float4*)(flat + bb*KTOT + k0 + kk4*4);
    lds[kk4*4+0][bb] = v.x; lds[kk4*4+1][bb] = v.y;
    lds[kk4*4+2][bb] = v.z; lds[kk4*4+3][bb] = v.w;
  }
  __syncthreads();
  int c0 = n0 + t*2;
  float2 acc[16];
  #pragma unroll
  for (int b=0;b<16;b++) acc[b] = make_float2(0.f,0.f);
  const float* Wp = W + (size_t)k0*NCOL + c0;
  for (int kk=0; kk<KC; kk+=2) {
    float2 w0 = *(const float2*)(Wp + (size_t)kk*NCOL);
    float2 w1 = *(const float2*)(Wp + (size_t)(kk+1)*NCOL);
    const float4* f0 = (const float4*)&lds[kk][0];
    const float4* f1 = (const float4*)&lds[kk+1][0];
    #pragma unroll
    for (int q=0;q<4;q++) {
      float4 fa = f0[q], fb = f1[q];
      float fs0[4] = {fa.x,fa.y,fa.z,fa.w};
      float fs1[4] = {fb.x,fb.y,fb.z,fb.w};
      #pragma unroll
      for (int j=0;j<4;j++) {
        int b = q*4+j;
        acc[b].x=fmaf(fs0[j],w0.x,acc[b].x); acc[b].y=fmaf(fs0[j],w0.y,acc[b].y);
        acc[b].x=fmaf(fs1[j],w1.x,acc[b].x); acc[b].y=fmaf(fs1[j],w1.y,acc[b].y);
      }
    }
  }
  float* p = part + (size_t)blockIdx.y*OUTSZ;
  #pragma unroll
  for (int b=0;b<16;b++) *(float2*)(p + b*NCOL + c0) = acc[b];
}

// out = sum_s part[s] + bias
__global__ void k_reduce(const float* __restrict__ part, const float* __restrict__ bias,
                         float* __restrict__ out) {
  int idx = blockIdx.x*256 + threadIdx.x; // OUTSZ
  float acc = bias[idx % NCOL];
  #pragma unroll 8
  for (int s=0;s<KS;s++) acc += part[(size_t)s*OUTSZ + idx];
  out[idx] = acc;
}

extern "C" void kernel_launch(void* const* d_in, const int* in_sizes, int n_in,
                              void* d_out, int out_size, void* d_ws, size_t ws_size,
                              hipStream_t stream) {
  const float* x        = (const float*)d_in[0];
  const float* W_in     = (const float*)d_in[1];
  const float* b_in     = (const float*)d_in[2];
  const float* W_inproj = (const float*)d_in[3];
  const float* conv_w   = (const float*)d_in[4];
  const float* conv_b   = (const float*)d_in[5];
  const float* W_xproj  = (const float*)d_in[6];
  const float* W_dt     = (const float*)d_in[7];
  const float* b_dt     = (const float*)d_in[8];
  const float* A_log    = (const float*)d_in[9];
  const float* Dp       = (const float*)d_in[10];
  const float* W_out    = (const float*)d_in[11];
  const float* W_outproj= (const float*)d_in[12];
  const float* b_outproj= (const float*)d_in[13];
  float* out = (float*)d_out;
  float* ws  = (float*)d_ws;

  float* h     = ws;            // 1048576
  float* u_pre = ws + 1048576;  // 2097152
  float* z     = ws + 3145728;  // 2097152
  float* u     = ws + 5242880;  // 2097152
  float* xdbc  = ws + 7340032;  // 327680
  float* Hc    = ws + 7667712;  // 2097152 (NB*DI*CH*16)
  float* Sdt   = ws + 9764864;  // 131072
  float* Hst   = ws + 9895936;  // 2097152
  float* ym    = ws + 11993088; // 2097152
  float* mo    = ws + 14090240; // 1048576
  float* part  = ws + 15138816; // 12582912 (KS*OUTSZ) -> total ~111 MB

  k_in     <<<4096, 256, 0, stream>>>(x, W_in, b_in, h);
  k_inproj <<<1024, 256, 0, stream>>>(h, W_inproj, u_pre, z);
  k_conv   <<<8192, 256, 0, stream>>>(u_pre, conv_w, conv_b, u);
  k_xproj  <<<1280, 256, 0, stream>>>(u, W_xproj, xdbc);
  k_scan1  <<<512,  256, 0, stream>>>(u, xdbc, W_dt, b_dt, A_log, Hc, Sdt);
  k_scan2  <<<256,  256, 0, stream>>>(A_log, Hc, Sdt, Hst);
  k_scan3  <<<512,  256, 0, stream>>>(u, z, xdbc, W_dt, b_dt, A_log, Dp, Hst, ym);
  k_out    <<<1024, 256, 0, stream>>>(ym, W_out, mo);
  k_final  <<<dim3(6, KS), 256, 0, stream>>>(mo, W_outproj, part);
  k_reduce <<<192,  256, 0, stream>>>(part, b_outproj, out);
}